// Round 1
// 4871.218 us; speedup vs baseline: 1.1261x; 1.1261x over previous
//
#include <hip/hip_runtime.h>
#include <hip/hip_bf16.h>
#include <cstdio>

#define TT 512
#define NN 64
#define CC 512
#define HH 1024
#define PP 512
#define GG 4096           // 4*H
#define MPRE (TT*NN)      // 32768
#define TC 256            // timesteps per chunk
#define TCM (TC*NN)       // pre-chunk leading dim (rows)
#define NB 128            // recurrence blocks (8 h each)

typedef __attribute__((ext_vector_type(8))) short short8;
typedef __attribute__((ext_vector_type(4))) float floatx4;

__device__ __forceinline__ unsigned short f2bf(float f) {
  union { float f; unsigned u; } v; v.f = f;
  unsigned r = v.u + 0x7fffu + ((v.u >> 16) & 1u);
  return (unsigned short)(r >> 16);
}
__device__ __forceinline__ float bf2f(unsigned short u) {
  union { unsigned u; float f; } v; v.u = ((unsigned)u) << 16; return v.f;
}
__device__ __forceinline__ float sigm(float x) { return 1.f / (1.f + __expf(-x)); }
__device__ __forceinline__ float tanha(float x) { return 1.f - 2.f / (__expf(2.f * x) + 1.f); }

typedef const __attribute__((address_space(1))) void gvoid_t;
typedef __attribute__((address_space(3))) void lvoid_t;
__device__ __forceinline__ void gl2lds16(const void* g, void* l) {
  __builtin_amdgcn_global_load_lds((gvoid_t*)g, (lvoid_t*)l, 16, 0, 0);
}

__global__ void cast_f32_bf16(const float* __restrict__ src, unsigned short* __restrict__ dst, int n) {
  int i = (blockIdx.x * 256 + threadIdx.x) * 4;
  if (i < n) {
    float4 v = *(const float4*)(src + i);
    ushort4 o;
    o.x = f2bf(v.x); o.y = f2bf(v.y); o.z = f2bf(v.z); o.w = f2bf(v.w);
    *(ushort4*)(dst + i) = o;
  }
}

// dst[h][p] = (bf16) src[p][h]   (src is wo_w: P x H)
__global__ void transpose_cast(const float* __restrict__ src, unsigned short* __restrict__ dst) {
  int idx = blockIdx.x * 256 + threadIdx.x;
  if (idx < HH * PP) {
    int h = idx >> 9, p = idx & 511;
    dst[idx] = f2bf(src[p * HH + h]);
  }
}

// C[m][n] = sum_k A[m][k]*B[n][k] (+bias[n]); A: M x K, B: N x K, bf16.
// writeT: C stored transposed (C[n][m], leading dim M).
__global__ __launch_bounds__(256) void gemm_bt(
    const unsigned short* __restrict__ A, const unsigned short* __restrict__ B,
    const float* __restrict__ bias, unsigned short* __restrict__ C,
    int M, int N, int K, int writeT)
{
  __shared__ __align__(16) unsigned short As[128 * 32];
  __shared__ __align__(16) unsigned short Bs[128 * 32];
  const int tid = threadIdx.x;
  const int l = tid & 63, w = tid >> 6;
  const int wm = w >> 1, wn = w & 1;
  const int lane16 = l & 15, quad = l >> 4;
  const int rowA0 = blockIdx.x * 128, rowB0 = blockIdx.y * 128;
  floatx4 acc[4][4] = {};
  for (int kk = 0; kk < K; kk += 32) {
    __syncthreads();
#pragma unroll
    for (int r = 0; r < 2; ++r) {
      const int e = r * 256 + tid;
      const int row = e >> 2, kgrp = (e & 3) << 3;
      gl2lds16(A + (size_t)(rowA0 + row) * K + kk + kgrp, As + (r * 256 + w * 64) * 8);
      gl2lds16(B + (size_t)(rowB0 + row) * K + kk + kgrp, Bs + (r * 256 + w * 64) * 8);
    }
    __syncthreads();
    short8 af[4], bf[4];
#pragma unroll
    for (int mt = 0; mt < 4; ++mt) af[mt] = *(const short8*)&As[(wm * 64 + mt * 16 + lane16) * 32 + quad * 8];
#pragma unroll
    for (int nt = 0; nt < 4; ++nt) bf[nt] = *(const short8*)&Bs[(wn * 64 + nt * 16 + lane16) * 32 + quad * 8];
#pragma unroll
    for (int mt = 0; mt < 4; ++mt)
#pragma unroll
      for (int nt = 0; nt < 4; ++nt)
        acc[mt][nt] = __builtin_amdgcn_mfma_f32_16x16x32_bf16(af[mt], bf[nt], acc[mt][nt], 0, 0, 0);
  }
#pragma unroll
  for (int mt = 0; mt < 4; ++mt) {
    const int m0 = rowA0 + wm * 64 + mt * 16 + quad * 4;
#pragma unroll
    for (int nt = 0; nt < 4; ++nt) {
      const int col = rowB0 + wn * 64 + nt * 16 + lane16;
      const float bv = bias ? bias[col] : 0.f;
      if (writeT) {
        ushort4 o;
        o.x = f2bf(acc[mt][nt][0] + bv); o.y = f2bf(acc[mt][nt][1] + bv);
        o.z = f2bf(acc[mt][nt][2] + bv); o.w = f2bf(acc[mt][nt][3] + bv);
        *(ushort4*)(C + (size_t)col * M + m0) = o;
      } else {
#pragma unroll
        for (int j = 0; j < 4; ++j) C[(size_t)(m0 + j) * N + col] = f2bf(acc[mt][nt][j] + bv);
      }
    }
  }
}

// act2 layout (per parity buffer, 16384 qwords = 128 KB):
//   qword index = ks*512 + region*256 + wv*64 + lane
//   holds act[n = wv*16 + (lane&15)][k = ks*32 + (lane>>4)*8 + region*4 + (0..3)] bf16x4.
// Consumer wave wv, tile ks: two fully-contiguous 512 B loads (lane*8B) -> A-frag.
// Producer (block b owns h = b*8 .. b*8+7): thread (w,l) computes h = b*8+2w+{0,1},
// stores one packed dword at:  v=4*(b&3)+w; q=v>>2; r=(v>>1)&1; s=v&1;
//   dword = ( (b>>2)*512 + r*256 + (l>>4)*64 + q*16 + (l&15) )*2 + s
//
// Synchronization: distributed flag barrier. Block b publishes flags[b]=t+1 after its
// act slice is drained to the coherence point; wave 0 of every block polls all NB flags
// (2 per lane, coalesced) until min >= t+1. No contended atomics. The out-projection
// for step t-1 is issued AFTER the flag store so its MFMA chain + HBM stores overlap
// the poll instead of delaying the release.
__global__ __launch_bounds__(256, 1) void lstm_rec(
    const unsigned short* __restrict__ preC,  // [4096][TCM] bf16
    const unsigned short* __restrict__ Wc,    // [4096][1024] bf16 (wr_w @ wo_w)
    const unsigned short* __restrict__ wo,    // [512][1024] bf16
    const float* __restrict__ wcp,            // [3072] peephole
    const void* __restrict__ lengths,         // int32 or int64 (auto-detected)
    unsigned long long* __restrict__ act2,    // [2][16384] qwords (zeroed)
    float* __restrict__ c_buf,                // [64][1024] f32 carry (zeroed)
    float* __restrict__ out,                  // [512][64][512]
    unsigned* __restrict__ flags,             // [NB] zeroed
    int t0, int t1, int last)
{
  __shared__ __align__(16) unsigned short Wc_lds[32 * 1032]; // 66 KB
  __shared__ float g_lds[64][33];                            // 8.4 KB  (74.5 KB total)
  const int tid = threadIdx.x, b = blockIdx.x;
  const int l = tid & 63, w = tid >> 6;
  const int lane16 = l & 15, quad = l >> 4;
  const int ptile = b & 31, kgr = b >> 5;     // kgr in 0..3 -> out replica group

  const int* L32 = (const int*)lengths;
  const bool is64 = (L32[1] == 0);

  // stage Wc: local row = gate*8 + hl  <-  Wc row gate*1024 + b*8 + hl
  for (int r = 0; r < 16; ++r) {
    int e = r * 256 + tid;
    int row = e >> 7, k = (e & 127) << 3;
    int gate = row >> 3, hl = row & 7;
    *(short8*)&Wc_lds[row * 1032 + k] =
        *(const short8*)&Wc[(size_t)(gate * 1024 + b * 8 + hl) * 1024 + k];
  }

  // gate-math thread (n=l, h = hb + kk, kk=0..1)
  const int hb = b * 8 + 2 * w;
  float cst[2], wci[2], wcf[2], wco[2];
#pragma unroll
  for (int kk = 0; kk < 2; ++kk) {
    cst[kk] = c_buf[l * HH + hb + kk];
    wci[kk] = wcp[hb + kk];
    wcf[kk] = wcp[1024 + hb + kk];
    wco[kk] = wcp[2048 + hb + kk];
  }
  // producer dword slot (constant across steps)
  const int v_ = (b & 3) * 4 + w;
  const int sq = v_ >> 2, sr = (v_ >> 1) & 1, ss = v_ & 1;
  const int pdw = ((b >> 2) * 512 + sr * 256 + (l >> 4) * 64 + sq * 16 + (l & 15)) * 2 + ss;
  unsigned* const act2dw = (unsigned*)act2;
  __syncthreads();

  for (int t = t0; t <= t1; ++t) {
    if (t == t1 && !last) break;
    const bool gate_on = (t < t1);

    float pv[4][2];
    if (gate_on) {
      const int trel = (t - t0) * NN + l;
#pragma unroll
      for (int g = 0; g < 4; ++g)
#pragma unroll
        for (int kk = 0; kk < 2; ++kk)
          pv[g][kk] = bf2f(preC[(size_t)(g * 1024 + hb + kk) * TCM + trel]);
    }

    // coherent act fragment loads: per wave per ks, two contiguous 512 B loads
    const unsigned long long* aP = act2 + (size_t)((t + 1) & 1) * 16384 + w * 64 + l;
    short8 frag[32];
#pragma unroll
    for (int ks = 0; ks < 32; ++ks) {
      unsigned long long lo = __hip_atomic_load(aP + ks * 512,       __ATOMIC_RELAXED, __HIP_MEMORY_SCOPE_AGENT);
      unsigned long long hi = __hip_atomic_load(aP + ks * 512 + 256, __ATOMIC_RELAXED, __HIP_MEMORY_SCOPE_AGENT);
      union { unsigned long long q[2]; short8 v; } u;
      u.q[0] = lo; u.q[1] = hi;
      frag[ks] = u.v;
    }

    if (gate_on) {
      floatx4 accg[2] = {};
#pragma unroll
      for (int ks = 0; ks < 32; ++ks) {
#pragma unroll
        for (int tt = 0; tt < 2; ++tt) {
          short8 bb = *(const short8*)&Wc_lds[(tt * 16 + lane16) * 1032 + ks * 32 + quad * 8];
          accg[tt] = __builtin_amdgcn_mfma_f32_16x16x32_bf16(frag[ks], bb, accg[tt], 0, 0, 0);
        }
      }

      // dump g tiles: rows n = w*16+quad*4+j, cols c = tt*16+lane16 (c -> gate=c>>3, hl=c&7)
#pragma unroll
      for (int tt = 0; tt < 2; ++tt)
#pragma unroll
        for (int j = 0; j < 4; ++j)
          g_lds[w * 16 + quad * 4 + j][tt * 16 + lane16] = accg[tt][j];
      __syncthreads();

      unsigned packed = 0;
#pragma unroll
      for (int kk = 0; kk < 2; ++kk) {
        float gi = g_lds[l][0 * 8 + 2 * w + kk] + pv[0][kk];
        float gf = g_lds[l][1 * 8 + 2 * w + kk] + pv[1][kk];
        float go = g_lds[l][2 * 8 + 2 * w + kk] + pv[2][kk];
        float gc = g_lds[l][3 * 8 + 2 * w + kk] + pv[3][kk];
        float ig = sigm(gi + wci[kk] * cst[kk]);
        float fg = sigm(gf + wcf[kk] * cst[kk]);
        float cc = fg * cst[kk] + ig * tanha(gc);
        float og = sigm(go + wco[kk] * cc);
        cst[kk] = cc;
        packed |= (unsigned)f2bf(og * tanha(cc)) << (16 * kk);
      }
      __hip_atomic_store(act2dw + (size_t)(t & 1) * 32768 + pdw, packed,
                         __ATOMIC_RELAXED, __HIP_MEMORY_SCOPE_AGENT);

      __builtin_amdgcn_s_waitcnt(0);   // every wave drains its own coherent store
      __syncthreads();                 // all waves of this block drained
      if (tid == 0) {
        __atomic_signal_fence(__ATOMIC_SEQ_CST);
        __hip_atomic_store(&flags[b], (unsigned)(t + 1),
                           __ATOMIC_RELAXED, __HIP_MEMORY_SCOPE_AGENT);
      }
    }

    // out projection for step t-1; issued after flag release so it overlaps the poll.
    // 4 replica groups, wave w==kgr writes n rows [w*16,+16)
    if (w == kgr && t > 0) {
      floatx4 acco = {0.f, 0.f, 0.f, 0.f};
      const unsigned short* worow = wo + (size_t)(ptile * 16 + lane16) * 1024 + quad * 8;
#pragma unroll
      for (int ks = 0; ks < 32; ++ks) {
        short8 bo = *(const short8*)(worow + ks * 32);
        acco = __builtin_amdgcn_mfma_f32_16x16x32_bf16(frag[ks], bo, acco, 0, 0, 0);
      }
      const int p = ptile * 16 + lane16;
#pragma unroll
      for (int j = 0; j < 4; ++j) {
        const int n = w * 16 + quad * 4 + j;
        const int ln = is64 ? (int)((const long long*)lengths)[n] : L32[n];
        out[(size_t)((t - 1) * NN + n) * PP + p] = ((t - 1) < ln) ? acco[j] : 0.f;
      }
    }

    if (gate_on) {
      if (w == 0) {
        const unsigned tgt = (unsigned)(t + 1);
        while (1) {
          unsigned f0 = __hip_atomic_load(&flags[2 * l],     __ATOMIC_RELAXED, __HIP_MEMORY_SCOPE_AGENT);
          unsigned f1 = __hip_atomic_load(&flags[2 * l + 1], __ATOMIC_RELAXED, __HIP_MEMORY_SCOPE_AGENT);
          if (__all((f0 >= tgt) && (f1 >= tgt))) break;
          __builtin_amdgcn_s_sleep(1);
        }
        __atomic_signal_fence(__ATOMIC_SEQ_CST);
      }
      __syncthreads();
    }
  }
#pragma unroll
  for (int kk = 0; kk < 2; ++kk) c_buf[l * HH + hb + kk] = cst[kk];
}

extern "C" void kernel_launch(void* const* d_in, const int* in_sizes, int n_in,
                              void* d_out, int out_size, void* d_ws, size_t ws_size,
                              hipStream_t stream) {
  (void)in_sizes; (void)n_in; (void)out_size;
  const float* x    = (const float*)d_in[0];
  const void*  len  = d_in[1];
  const float* wx_w = (const float*)d_in[2];
  const float* wx_b = (const float*)d_in[3];
  const float* wr_w = (const float*)d_in[4];
  const float* wo_w = (const float*)d_in[5];
  const float* wc   = (const float*)d_in[6];
  float* out = (float*)d_out;

  char* ws = (char*)d_ws; size_t off = 0;
  auto alloc = [&](size_t b) { void* p = ws + off; off += (b + 255) & ~(size_t)255; return p; };
  unsigned short* x_bf  = (unsigned short*)alloc((size_t)MPRE * CC * 2);
  unsigned short* wx_bf = (unsigned short*)alloc((size_t)GG * CC * 2);
  unsigned short* wr_bf = (unsigned short*)alloc((size_t)GG * PP * 2);
  unsigned short* wo_bf = (unsigned short*)alloc((size_t)PP * HH * 2);
  unsigned short* woT   = (unsigned short*)alloc((size_t)HH * PP * 2);
  unsigned short* Wc_bf = (unsigned short*)alloc((size_t)GG * HH * 2);
  unsigned short* preC  = (unsigned short*)alloc((size_t)GG * TCM * 2);
  unsigned long long* act2 = (unsigned long long*)alloc((size_t)2 * 16384 * 8);
  float*          c_buf = (float*)alloc((size_t)NN * HH * 4);
  unsigned* flags = (unsigned*)alloc(512);
  if (off > ws_size) {
    fprintf(stderr, "kernel_launch: workspace too small (%zu needed, %zu given)\n", off, ws_size);
    return;
  }

  // zero act2 double-buffer + c carry + flags (contiguous region)
  hipMemsetAsync(act2, 0, (size_t)2 * 16384 * 8 + (size_t)NN * HH * 4 + 512, stream);

  int n1 = MPRE * CC; cast_f32_bf16<<<dim3((n1 / 4 + 255) / 256), dim3(256), 0, stream>>>(x, x_bf, n1);
  int n2 = GG * CC;   cast_f32_bf16<<<dim3((n2 / 4 + 255) / 256), dim3(256), 0, stream>>>(wx_w, wx_bf, n2);
  int n3 = GG * PP;   cast_f32_bf16<<<dim3((n3 / 4 + 255) / 256), dim3(256), 0, stream>>>(wr_w, wr_bf, n3);
  int n4 = PP * HH;   cast_f32_bf16<<<dim3((n4 / 4 + 255) / 256), dim3(256), 0, stream>>>(wo_w, wo_bf, n4);
  transpose_cast<<<dim3((HH * PP + 255) / 256), dim3(256), 0, stream>>>(wo_w, woT);

  // W_comb = wr_w @ wo_w  (4096 x 1024)
  gemm_bt<<<dim3(GG / 128, HH / 128), dim3(256), 0, stream>>>(wr_bf, woT, nullptr, Wc_bf, GG, HH, PP, 0);

  for (int chunk = 0; chunk < TT / TC; ++chunk) {
    const int t0 = chunk * TC, t1 = t0 + TC;
    const int last = (t1 == TT) ? 1 : 0;
    gemm_bt<<<dim3(TCM / 128, GG / 128), dim3(256), 0, stream>>>(
        x_bf + (size_t)t0 * NN * CC, wx_bf, wx_b, preC, TCM, GG, CC, 1);

    const unsigned short* a0 = preC; const unsigned short* a1 = Wc_bf; const unsigned short* a2 = wo_bf;
    const float* a3 = wc; const void* a4 = len; unsigned long long* a5 = act2; float* a6c = c_buf;
    float* a7 = out; unsigned* a8 = flags; int a9 = t0, a10 = t1, a11 = last;
    void* args[12] = { &a0, &a1, &a2, &a3, &a4, &a5, &a6c, &a7, &a8, &a9, &a10, &a11 };
    hipError_t ce = hipLaunchCooperativeKernel((void*)lstm_rec, dim3(NB), dim3(256), args, 0, stream);
    if (ce != hipSuccess) {
      // fallback: plain launch (grid 128 <= 256 CUs -> co-resident; custom barrier, no grid.sync)
      lstm_rec<<<dim3(NB), dim3(256), 0, stream>>>(a0, a1, a2, a3, a4, a5, a6c, a7, a8, a9, a10, a11);
    }
  }
}

// Round 2
// 4821.706 us; speedup vs baseline: 1.1377x; 1.0103x over previous
//
#include <hip/hip_runtime.h>
#include <hip/hip_bf16.h>
#include <cstdio>

#define TT 512
#define NN 64
#define CC 512
#define HH 1024
#define PP 512
#define GG 4096           // 4*H
#define MPRE (TT*NN)      // 32768
#define TC 256            // timesteps per chunk
#define TCM (TC*NN)       // pre-chunk leading dim (rows)
#define NB 64             // recurrence blocks (16 h each)

typedef __attribute__((ext_vector_type(8))) short short8;
typedef __attribute__((ext_vector_type(4))) float floatx4;

__device__ __forceinline__ unsigned short f2bf(float f) {
  union { float f; unsigned u; } v; v.f = f;
  unsigned r = v.u + 0x7fffu + ((v.u >> 16) & 1u);
  return (unsigned short)(r >> 16);
}
__device__ __forceinline__ float bf2f(unsigned short u) {
  union { unsigned u; float f; } v; v.u = ((unsigned)u) << 16; return v.f;
}
__device__ __forceinline__ float sigm(float x) { return 1.f / (1.f + __expf(-x)); }
__device__ __forceinline__ float tanha(float x) { return 1.f - 2.f / (__expf(2.f * x) + 1.f); }

typedef const __attribute__((address_space(1))) void gvoid_t;
typedef __attribute__((address_space(3))) void lvoid_t;
__device__ __forceinline__ void gl2lds16(const void* g, void* l) {
  __builtin_amdgcn_global_load_lds((gvoid_t*)g, (lvoid_t*)l, 16, 0, 0);
}

__global__ void cast_f32_bf16(const float* __restrict__ src, unsigned short* __restrict__ dst, int n) {
  int i = (blockIdx.x * 256 + threadIdx.x) * 4;
  if (i < n) {
    float4 v = *(const float4*)(src + i);
    ushort4 o;
    o.x = f2bf(v.x); o.y = f2bf(v.y); o.z = f2bf(v.z); o.w = f2bf(v.w);
    *(ushort4*)(dst + i) = o;
  }
}

// dst[h][p] = (bf16) src[p][h]   (src is wo_w: P x H)
__global__ void transpose_cast(const float* __restrict__ src, unsigned short* __restrict__ dst) {
  int idx = blockIdx.x * 256 + threadIdx.x;
  if (idx < HH * PP) {
    int h = idx >> 9, p = idx & 511;
    dst[idx] = f2bf(src[p * HH + h]);
  }
}

// C[m][n] = sum_k A[m][k]*B[n][k] (+bias[n]); A: M x K, B: N x K, bf16.
// writeT: C stored transposed (C[n][m], leading dim M).
__global__ __launch_bounds__(256) void gemm_bt(
    const unsigned short* __restrict__ A, const unsigned short* __restrict__ B,
    const float* __restrict__ bias, unsigned short* __restrict__ C,
    int M, int N, int K, int writeT)
{
  __shared__ __align__(16) unsigned short As[128 * 32];
  __shared__ __align__(16) unsigned short Bs[128 * 32];
  const int tid = threadIdx.x;
  const int l = tid & 63, w = tid >> 6;
  const int wm = w >> 1, wn = w & 1;
  const int lane16 = l & 15, quad = l >> 4;
  const int rowA0 = blockIdx.x * 128, rowB0 = blockIdx.y * 128;
  floatx4 acc[4][4] = {};
  for (int kk = 0; kk < K; kk += 32) {
    __syncthreads();
#pragma unroll
    for (int r = 0; r < 2; ++r) {
      const int e = r * 256 + tid;
      const int row = e >> 2, kgrp = (e & 3) << 3;
      gl2lds16(A + (size_t)(rowA0 + row) * K + kk + kgrp, As + (r * 256 + w * 64) * 8);
      gl2lds16(B + (size_t)(rowB0 + row) * K + kk + kgrp, Bs + (r * 256 + w * 64) * 8);
    }
    __syncthreads();
    short8 af[4], bf[4];
#pragma unroll
    for (int mt = 0; mt < 4; ++mt) af[mt] = *(const short8*)&As[(wm * 64 + mt * 16 + lane16) * 32 + quad * 8];
#pragma unroll
    for (int nt = 0; nt < 4; ++nt) bf[nt] = *(const short8*)&Bs[(wn * 64 + nt * 16 + lane16) * 32 + quad * 8];
#pragma unroll
    for (int mt = 0; mt < 4; ++mt)
#pragma unroll
      for (int nt = 0; nt < 4; ++nt)
        acc[mt][nt] = __builtin_amdgcn_mfma_f32_16x16x32_bf16(af[mt], bf[nt], acc[mt][nt], 0, 0, 0);
  }
#pragma unroll
  for (int mt = 0; mt < 4; ++mt) {
    const int m0 = rowA0 + wm * 64 + mt * 16 + quad * 4;
#pragma unroll
    for (int nt = 0; nt < 4; ++nt) {
      const int col = rowB0 + wn * 64 + nt * 16 + lane16;
      const float bv = bias ? bias[col] : 0.f;
      if (writeT) {
        ushort4 o;
        o.x = f2bf(acc[mt][nt][0] + bv); o.y = f2bf(acc[mt][nt][1] + bv);
        o.z = f2bf(acc[mt][nt][2] + bv); o.w = f2bf(acc[mt][nt][3] + bv);
        *(ushort4*)(C + (size_t)col * M + m0) = o;
      } else {
#pragma unroll
        for (int j = 0; j < 4; ++j) C[(size_t)(m0 + j) * N + col] = f2bf(acc[mt][nt][j] + bv);
      }
    }
  }
}

// act2 layout (per parity buffer, 16384 qwords = 128 KB):
//   qword index = ks*512 + region*256 + wv*64 + lane
//   holds act[n = wv*16 + (lane&15)][k = ks*32 + (lane>>4)*8 + region*4 + (0..3)] bf16x4.
// Consumer wave wv, tile ks: two fully-contiguous 512 B loads (lane*8B) -> A-frag.
// Producer (NB=64: block b owns h = b*16 .. b*16+15): thread (w,l) computes
// h = hb..hb+3 with hb = b*16+4w, n = l, and stores ONE packed qword (4 bf16):
//   ks = b>>1; region = w&1; octet = 2*(b&1) + (w>>1);
//   qword = ks*512 + region*256 + (l>>4)*64 + octet*16 + (l&15)
//
// Synchronization: distributed flag barrier (64 flags, one per block). Block b
// publishes flags[b]=t+1 after its act slice is drained; wave 0 of every block
// polls all 64 flags (1/lane, coalesced). Out-projection for step t-1 is issued
// AFTER the flag store so it overlaps the poll.
__global__ __launch_bounds__(256, 1) void lstm_rec(
    const unsigned short* __restrict__ preC,  // [4096][TCM] bf16
    const unsigned short* __restrict__ Wc,    // [4096][1024] bf16 (wr_w @ wo_w)
    const unsigned short* __restrict__ wo,    // [512][1024] bf16
    const float* __restrict__ wcp,            // [3072] peephole
    const void* __restrict__ lengths,         // int32 or int64 (auto-detected)
    unsigned long long* __restrict__ act2,    // [2][16384] qwords (zeroed)
    float* __restrict__ c_buf,                // [64][1024] f32 carry (zeroed)
    float* __restrict__ out,                  // [512][64][512]
    unsigned* __restrict__ flags,             // [NB] zeroed
    int t0, int t1, int last)
{
  __shared__ __align__(16) unsigned short Wc_lds[64 * 1032]; // 132 KB
  __shared__ float g_lds[64][65];                            // 16.6 KB (148.7 KB total)
  const int tid = threadIdx.x, b = blockIdx.x;
  const int l = tid & 63, w = tid >> 6;
  const int lane16 = l & 15, quad = l >> 4;
  const int ptile = b & 31, kgr = b >> 5;     // kgr in 0..1 -> out replica group

  const int* L32 = (const int*)lengths;
  const bool is64 = (L32[1] == 0);

  // stage Wc: local row = gate*16 + hl  <-  Wc row gate*1024 + b*16 + hl
  for (int r = 0; r < 32; ++r) {
    int e = r * 256 + tid;
    int row = e >> 7, k = (e & 127) << 3;
    int gate = row >> 4, hl = row & 15;
    *(short8*)&Wc_lds[row * 1032 + k] =
        *(const short8*)&Wc[(size_t)(gate * 1024 + b * 16 + hl) * 1024 + k];
  }

  // gate-math thread (n=l, h = hb + kk, kk=0..3)
  const int hb = b * 16 + 4 * w;
  float cst[4], wci[4], wcf[4], wco[4];
#pragma unroll
  for (int kk = 0; kk < 4; ++kk) {
    cst[kk] = c_buf[l * HH + hb + kk];
    wci[kk] = wcp[hb + kk];
    wcf[kk] = wcp[1024 + hb + kk];
    wco[kk] = wcp[2048 + hb + kk];
  }
  // producer qword slot (constant across steps)
  const int octet = 2 * (b & 1) + (w >> 1);
  const int region = w & 1;
  const int ksb = b >> 1;
  const int pq = ksb * 512 + region * 256 + (l >> 4) * 64 + octet * 16 + (l & 15);
  __syncthreads();

  for (int t = t0; t <= t1; ++t) {
    if (t == t1 && !last) break;
    const bool gate_on = (t < t1);

    float pv[4][4];
    if (gate_on) {
      const int trel = (t - t0) * NN + l;
#pragma unroll
      for (int g = 0; g < 4; ++g)
#pragma unroll
        for (int kk = 0; kk < 4; ++kk)
          pv[g][kk] = bf2f(preC[(size_t)(g * 1024 + hb + kk) * TCM + trel]);
    }

    // coherent act fragment loads: per wave per ks, two contiguous 512 B loads
    const unsigned long long* aP = act2 + (size_t)((t + 1) & 1) * 16384 + w * 64 + l;
    short8 frag[32];
#pragma unroll
    for (int ks = 0; ks < 32; ++ks) {
      unsigned long long lo = __hip_atomic_load(aP + ks * 512,       __ATOMIC_RELAXED, __HIP_MEMORY_SCOPE_AGENT);
      unsigned long long hi = __hip_atomic_load(aP + ks * 512 + 256, __ATOMIC_RELAXED, __HIP_MEMORY_SCOPE_AGENT);
      union { unsigned long long q[2]; short8 v; } u;
      u.q[0] = lo; u.q[1] = hi;
      frag[ks] = u.v;
    }

    if (gate_on) {
      floatx4 accg[4] = {};
#pragma unroll
      for (int ks = 0; ks < 32; ++ks) {
#pragma unroll
        for (int tt = 0; tt < 4; ++tt) {
          short8 bb = *(const short8*)&Wc_lds[(tt * 16 + lane16) * 1032 + ks * 32 + quad * 8];
          accg[tt] = __builtin_amdgcn_mfma_f32_16x16x32_bf16(frag[ks], bb, accg[tt], 0, 0, 0);
        }
      }

      // dump g tiles: rows n = w*16+quad*4+j, cols c = tt*16+lane16 (c -> gate=c>>4, hl=c&15)
#pragma unroll
      for (int tt = 0; tt < 4; ++tt)
#pragma unroll
        for (int j = 0; j < 4; ++j)
          g_lds[w * 16 + quad * 4 + j][tt * 16 + lane16] = accg[tt][j];
      __syncthreads();

      unsigned long long packed = 0;
#pragma unroll
      for (int kk = 0; kk < 4; ++kk) {
        float gi = g_lds[l][0 * 16 + 4 * w + kk] + pv[0][kk];
        float gf = g_lds[l][1 * 16 + 4 * w + kk] + pv[1][kk];
        float go = g_lds[l][2 * 16 + 4 * w + kk] + pv[2][kk];
        float gc = g_lds[l][3 * 16 + 4 * w + kk] + pv[3][kk];
        float ig = sigm(gi + wci[kk] * cst[kk]);
        float fg = sigm(gf + wcf[kk] * cst[kk]);
        float cc = fg * cst[kk] + ig * tanha(gc);
        float og = sigm(go + wco[kk] * cc);
        cst[kk] = cc;
        packed |= (unsigned long long)f2bf(og * tanha(cc)) << (16 * kk);
      }
      __hip_atomic_store(act2 + (size_t)(t & 1) * 16384 + pq, packed,
                         __ATOMIC_RELAXED, __HIP_MEMORY_SCOPE_AGENT);

      __builtin_amdgcn_s_waitcnt(0);   // every wave drains its own coherent store
      __syncthreads();                 // all waves of this block drained
      if (tid == 0) {
        __atomic_signal_fence(__ATOMIC_SEQ_CST);
        __hip_atomic_store(&flags[b], (unsigned)(t + 1),
                           __ATOMIC_RELAXED, __HIP_MEMORY_SCOPE_AGENT);
      }
    }

    // out projection for step t-1; issued after flag release so it overlaps the poll.
    // 2 replica groups; waves with (w>>1)==kgr write n rows [w*16,+16)
    if ((w >> 1) == kgr && t > 0) {
      floatx4 acco = {0.f, 0.f, 0.f, 0.f};
      const unsigned short* worow = wo + (size_t)(ptile * 16 + lane16) * 1024 + quad * 8;
#pragma unroll
      for (int ks = 0; ks < 32; ++ks) {
        short8 bo = *(const short8*)(worow + ks * 32);
        acco = __builtin_amdgcn_mfma_f32_16x16x32_bf16(frag[ks], bo, acco, 0, 0, 0);
      }
      const int p = ptile * 16 + lane16;
#pragma unroll
      for (int j = 0; j < 4; ++j) {
        const int n = w * 16 + quad * 4 + j;
        const int ln = is64 ? (int)((const long long*)lengths)[n] : L32[n];
        out[(size_t)((t - 1) * NN + n) * PP + p] = ((t - 1) < ln) ? acco[j] : 0.f;
      }
    }

    if (gate_on) {
      if (w == 0) {
        const unsigned tgt = (unsigned)(t + 1);
        while (1) {
          unsigned f = __hip_atomic_load(&flags[l], __ATOMIC_RELAXED, __HIP_MEMORY_SCOPE_AGENT);
          if (__all(f >= tgt)) break;
          __builtin_amdgcn_s_sleep(1);
        }
        __atomic_signal_fence(__ATOMIC_SEQ_CST);
      }
      __syncthreads();
    }
  }
#pragma unroll
  for (int kk = 0; kk < 4; ++kk) c_buf[l * HH + hb + kk] = cst[kk];
}

extern "C" void kernel_launch(void* const* d_in, const int* in_sizes, int n_in,
                              void* d_out, int out_size, void* d_ws, size_t ws_size,
                              hipStream_t stream) {
  (void)in_sizes; (void)n_in; (void)out_size;
  const float* x    = (const float*)d_in[0];
  const void*  len  = d_in[1];
  const float* wx_w = (const float*)d_in[2];
  const float* wx_b = (const float*)d_in[3];
  const float* wr_w = (const float*)d_in[4];
  const float* wo_w = (const float*)d_in[5];
  const float* wc   = (const float*)d_in[6];
  float* out = (float*)d_out;

  char* ws = (char*)d_ws; size_t off = 0;
  auto alloc = [&](size_t b) { void* p = ws + off; off += (b + 255) & ~(size_t)255; return p; };
  unsigned short* x_bf  = (unsigned short*)alloc((size_t)MPRE * CC * 2);
  unsigned short* wx_bf = (unsigned short*)alloc((size_t)GG * CC * 2);
  unsigned short* wr_bf = (unsigned short*)alloc((size_t)GG * PP * 2);
  unsigned short* wo_bf = (unsigned short*)alloc((size_t)PP * HH * 2);
  unsigned short* woT   = (unsigned short*)alloc((size_t)HH * PP * 2);
  unsigned short* Wc_bf = (unsigned short*)alloc((size_t)GG * HH * 2);
  unsigned short* preC  = (unsigned short*)alloc((size_t)GG * TCM * 2);
  unsigned long long* act2 = (unsigned long long*)alloc((size_t)2 * 16384 * 8);
  float*          c_buf = (float*)alloc((size_t)NN * HH * 4);
  unsigned* flags = (unsigned*)alloc(512);
  if (off > ws_size) {
    fprintf(stderr, "kernel_launch: workspace too small (%zu needed, %zu given)\n", off, ws_size);
    return;
  }

  // zero act2 double-buffer + c carry + flags (contiguous region)
  hipMemsetAsync(act2, 0, (size_t)2 * 16384 * 8 + (size_t)NN * HH * 4 + 512, stream);

  int n1 = MPRE * CC; cast_f32_bf16<<<dim3((n1 / 4 + 255) / 256), dim3(256), 0, stream>>>(x, x_bf, n1);
  int n2 = GG * CC;   cast_f32_bf16<<<dim3((n2 / 4 + 255) / 256), dim3(256), 0, stream>>>(wx_w, wx_bf, n2);
  int n3 = GG * PP;   cast_f32_bf16<<<dim3((n3 / 4 + 255) / 256), dim3(256), 0, stream>>>(wr_w, wr_bf, n3);
  int n4 = PP * HH;   cast_f32_bf16<<<dim3((n4 / 4 + 255) / 256), dim3(256), 0, stream>>>(wo_w, wo_bf, n4);
  transpose_cast<<<dim3((HH * PP + 255) / 256), dim3(256), 0, stream>>>(wo_w, woT);

  // W_comb = wr_w @ wo_w  (4096 x 1024)
  gemm_bt<<<dim3(GG / 128, HH / 128), dim3(256), 0, stream>>>(wr_bf, woT, nullptr, Wc_bf, GG, HH, PP, 0);

  for (int chunk = 0; chunk < TT / TC; ++chunk) {
    const int t0 = chunk * TC, t1 = t0 + TC;
    const int last = (t1 == TT) ? 1 : 0;
    gemm_bt<<<dim3(TCM / 128, GG / 128), dim3(256), 0, stream>>>(
        x_bf + (size_t)t0 * NN * CC, wx_bf, wx_b, preC, TCM, GG, CC, 1);

    const unsigned short* a0 = preC; const unsigned short* a1 = Wc_bf; const unsigned short* a2 = wo_bf;
    const float* a3 = wc; const void* a4 = len; unsigned long long* a5 = act2; float* a6c = c_buf;
    float* a7 = out; unsigned* a8 = flags; int a9 = t0, a10 = t1, a11 = last;
    void* args[12] = { &a0, &a1, &a2, &a3, &a4, &a5, &a6c, &a7, &a8, &a9, &a10, &a11 };
    hipError_t ce = hipLaunchCooperativeKernel((void*)lstm_rec, dim3(NB), dim3(256), args, 0, stream);
    if (ce != hipSuccess) {
      // fallback: plain launch (grid 64 <= 256 CUs -> co-resident; custom barrier, no grid.sync)
      lstm_rec<<<dim3(NB), dim3(256), 0, stream>>>(a0, a1, a2, a3, a4, a5, a6c, a7, a8, a9, a10, a11);
    }
  }
}